// Round 14
// baseline (324.771 us; speedup 1.0000x reference)
//
#include <hip/hip_runtime.h>
#include <stdint.h>

#define FEAT 128
#define ECH 2048   // edges per econv block
#define CAP 200000 // per-partition edge capacity
#define DEGB 512   // degree-count blocks in fused k_dg

typedef short bf16x8 __attribute__((ext_vector_type(8)));
typedef float f32x4 __attribute__((ext_vector_type(4)));
typedef float f32x2 __attribute__((ext_vector_type(2)));

__device__ __forceinline__ float bfs(unsigned short u) {
    uint32_t t = ((uint32_t)u) << 16;
    return __builtin_bit_cast(float, t);
}
__device__ __forceinline__ unsigned short f2bf(float f) {
    uint32_t u = __builtin_bit_cast(uint32_t, f);
    u += 0x7fffu + ((u >> 16) & 1u);
    return (unsigned short)(u >> 16);
}

// ---- fused prep: econv blocks [0,NE) | W blocks [NE,NE+64) | bias [+18) -
__launch_bounds__(256)
__global__ void k_prep(const int* __restrict__ ei,
                       int* __restrict__ dstb, int* __restrict__ srcb,
                       int* __restrict__ bcnt, int* __restrict__ deg,
                       int E, int n, int psz, int NE,
                       const void* W1, const void* W2,
                       const void* b1, const void* b2,
                       const void* Wfc, const void* bfc,
                       unsigned short* Wth1, unsigned short* Wth2,
                       float* b1f, float* b2f, float* Wfcf, float* bfcf) {
    int t = threadIdx.x;

    if ((int)blockIdx.x >= NE) {
        __shared__ int hits;
        int blk = blockIdx.x - NE;
        const void* sampsrc = (blk < 32) ? W1 : (blk < 64 ? W2 : Wfc);
        const uint32_t* samp = (const uint32_t*)sampsrc;
        if (t == 0) hits = 0;
        __syncthreads();
        unsigned ew = (samp[t] >> 7) & 0xFFu;
        unsigned long long bl = __ballot(ew >= 0x60u && ew <= 0x90u);
        if ((t & 63) == 0) atomicAdd(&hits, (int)__popcll(bl));
        __syncthreads();
        int isbf = (2 * hits > 256);

        if (blk < 64) {
            const void* W = (blk < 32) ? W1 : W2;
            unsigned short* th = (blk < 32) ? Wth1 : Wth2;
            int base = (blk & 31) * 512;
            #pragma unroll
            for (int j = 0; j < 2; j++) {
                int idx = base + t * 2 + j;
                int nn = idx >> 7, k = idx & 127;
                int si = k * 128 + nn;
                float f = isbf ? bfs(((const unsigned short*)W)[si])
                               : ((const float*)W)[si];
                th[nn * 128 + k] = f2bf(f);
            }
        } else {
            int i = (blk - 64) * 256 + t;
            if (i >= 4384) return;
            const void* src; float* dst; int off;
            if (i < 128)       { src = b1;  dst = b1f;  off = i; }
            else if (i < 256)  { src = b2;  dst = b2f;  off = i - 128; }
            else if (i < 4352) { src = Wfc; dst = Wfcf; off = i - 256; }
            else               { src = bfc; dst = bfcf; off = i - 4352; }
            dst[off] = isbf ? bfs(((const unsigned short*)src)[off])
                            : ((const float*)src)[off];
        }
        return;
    }

    // ---- econv part (+ zero its deg slice) ----
    __shared__ int lflag;
    __shared__ int cnt[8], lofs[8], gbase[8];
    __shared__ int stage_s[ECH];
    __shared__ int stage_d[ECH];
    __shared__ char sb[ECH];
    if (t < 128) {
        int di = blockIdx.x * 128 + t;
        if (di < n) deg[di] = 0;
    }
    if (t == 0) lflag = 0;
    if (t < 8) cnt[t] = 0;
    __syncthreads();
    if (ei[1 + 2 * t] != 0) atomicOr(&lflag, 1);   // odd words: 0 => int64
    __syncthreads();
    int is32 = lflag;

    int base = blockIdx.x * ECH;
    int s[8], d[8], p[8], slot[8];
    #pragma unroll
    for (int j = 0; j < 8; j++) {
        int e = base + j * 256 + t;
        int ss = 0, dd = 0;
        if (e < E) {
            ss = is32 ? ei[e]     : ei[2 * e];
            dd = is32 ? ei[E + e] : ei[2 * E + 2 * e];
            if ((unsigned)ss >= (unsigned)n) ss = 0;
            if ((unsigned)dd >= (unsigned)n) dd = 0;
            int pp = dd / psz;
            if (pp > 7) pp = 7;
            p[j] = pp;
            slot[j] = atomicAdd(&cnt[pp], 1);
        } else p[j] = -1;
        s[j] = ss; d[j] = dd;
    }
    __syncthreads();
    if (t == 0) {
        int acc = 0;
        #pragma unroll
        for (int i = 0; i < 8; i++) { lofs[i] = acc; acc += cnt[i]; }
    }
    __syncthreads();
    if (t < 8) gbase[t] = atomicAdd(&bcnt[t], cnt[t]);
    __syncthreads();
    #pragma unroll
    for (int j = 0; j < 8; j++) {
        if (p[j] >= 0) {
            int pos = lofs[p[j]] + slot[j];
            stage_s[pos] = s[j];
            stage_d[pos] = d[j];
            sb[pos] = (char)p[j];
        }
    }
    __syncthreads();
    int tot = lofs[7] + cnt[7];
    for (int i = t; i < tot; i += 256) {
        int pp = sb[i];
        int off = gbase[pp] + (i - lofs[pp]);
        if (off < CAP) {
            dstb[pp * CAP + off] = stage_d[i];
            srcb[pp * CAP + off] = stage_s[i];
        }
    }
}

// ---- GEMM tile body: hs_fp8 = fp8(X @ W), no dinv -----------------------
// fmt 0: raw input (f32/bf16 per-wave sample); fmt 2: fp8 act.
__device__ __forceinline__ void gemm_body(const void* __restrict__ X,
                                          const unsigned short* __restrict__ Wth,
                                          uint32_t* __restrict__ hs8,
                                          int n, int fmt, int tile, int l,
                                          unsigned char* __restrict__ ldsrow) {
    int quad = l >> 4;
    int m16 = l & 15;
    int r0 = tile * 16;

    int isbf;
    if (fmt != 0) isbf = 1;
    else {
        unsigned ew = (((const uint32_t*)X)[l] >> 7) & 0xFFu;
        unsigned long long bl = __ballot(ew >= 0x60u && ew <= 0x90u);
        isbf = ((int)__popcll(bl) * 2 > 64) ? 1 : 0;
    }

    int ra = r0 + m16;
    if (ra > n - 1) ra = n - 1;
    bf16x8 ah[4];
    if (fmt == 2) {
        const uint2* Xq = (const uint2*)X;   // 16 uint2 per 128-B fp8 row
        #pragma unroll
        for (int kt = 0; kt < 4; kt++) {
            uint2 v8 = Xq[ra * 16 + kt * 4 + quad];
            f32x2 p0 = __builtin_amdgcn_cvt_pk_f32_fp8((int)v8.x, false);
            f32x2 p1 = __builtin_amdgcn_cvt_pk_f32_fp8((int)v8.x, true);
            f32x2 p2 = __builtin_amdgcn_cvt_pk_f32_fp8((int)v8.y, false);
            f32x2 p3 = __builtin_amdgcn_cvt_pk_f32_fp8((int)v8.y, true);
            bf16x8 h;
            h[0] = (short)f2bf(p0.x); h[1] = (short)f2bf(p0.y);
            h[2] = (short)f2bf(p1.x); h[3] = (short)f2bf(p1.y);
            h[4] = (short)f2bf(p2.x); h[5] = (short)f2bf(p2.y);
            h[6] = (short)f2bf(p3.x); h[7] = (short)f2bf(p3.y);
            ah[kt] = h;
        }
    } else if (isbf) {
        const int4* Xv = (const int4*)X;
        #pragma unroll
        for (int kt = 0; kt < 4; kt++)
            ah[kt] = __builtin_bit_cast(bf16x8, Xv[ra * 16 + kt * 4 + quad]);
    } else {
        const float4* Xf = (const float4*)X;
        #pragma unroll
        for (int kt = 0; kt < 4; kt++) {
            int jj = kt * 4 + quad;
            float4 fa = Xf[ra * 32 + jj * 2];
            float4 fb = Xf[ra * 32 + jj * 2 + 1];
            float v[8] = {fa.x, fa.y, fa.z, fa.w, fb.x, fb.y, fb.z, fb.w};
            bf16x8 h;
            #pragma unroll
            for (int j = 0; j < 8; j++) h[j] = (short)f2bf(v[j]);
            ah[kt] = h;
        }
    }

    const int4* Wvh = (const int4*)Wth;
    #pragma unroll
    for (int nt = 0; nt < 8; nt++) {
        f32x4 acc = {0.f, 0.f, 0.f, 0.f};
        int brow = (nt * 16 + m16) * 16;
        #pragma unroll
        for (int kt = 0; kt < 4; kt++) {
            bf16x8 bh = __builtin_bit_cast(bf16x8, Wvh[brow + kt * 4 + quad]);
            acc = __builtin_amdgcn_mfma_f32_16x16x32_bf16(ah[kt], bh, acc, 0, 0, 0);
        }
        #pragma unroll
        for (int reg = 0; reg < 4; reg++) {
            float v = acc[reg];
            int pk = __builtin_amdgcn_cvt_pk_fp8_f32(v, v, 0, false);
            ldsrow[(quad * 4 + reg) * 128 + nt * 16 + m16] = (unsigned char)(pk & 0xFF);
        }
    }
    __syncthreads();
    const uint32_t* l32 = (const uint32_t*)ldsrow;
    #pragma unroll
    for (int i = 0; i < 8; i++) {
        int idx = i * 64 + l;
        int row = idx >> 5;
        int grow = r0 + row;
        if (grow < n) hs8[grow * 32 + (idx & 31)] = l32[idx];
    }
}

// ---- fused: degree count [0,DEGB) || GEMM layer-1 [DEGB,..) -------------
__launch_bounds__(256)
__global__ void k_dg(const int* __restrict__ dstb, const int* __restrict__ bcnt,
                     int* __restrict__ deg,
                     const void* __restrict__ X,
                     const unsigned short* __restrict__ Wth,
                     uint32_t* __restrict__ hs8, int n) {
    __shared__ unsigned char lds8[4][16 * 128];
    int b = blockIdx.x;
    if (b < DEGB) {
        int p = b & 7;
        int nb = DEGB >> 3;
        int cnt = bcnt[p]; if (cnt > CAP) cnt = CAP;
        const int* db = dstb + p * CAP;
        for (int i = (b >> 3) * 256 + threadIdx.x; i < cnt; i += nb * 256)
            atomicAdd(&deg[db[i]], 1);
        return;
    }
    int wave = threadIdx.x >> 6;
    int l = threadIdx.x & 63;
    gemm_body(X, Wth, hs8, n, 0, (b - DEGB) * 4 + wave, l, lds8[wave]);
}

__launch_bounds__(256)
__global__ void k_gemm(const void* __restrict__ X,
                       const unsigned short* __restrict__ Wth,
                       uint32_t* __restrict__ hs8, int n, int fmt) {
    __shared__ unsigned char lds8[4][16 * 128];
    int wave = threadIdx.x >> 6;
    int l = threadIdx.x & 63;
    gemm_body(X, Wth, hs8, n, fmt, blockIdx.x * 4 + wave, l, lds8[wave]);
}

// ---- block sums (+ fused dinv) ------------------------------------------
__global__ void k_bsum(const int* __restrict__ deg, int* __restrict__ bsum,
                       float* __restrict__ dinv, int n) {
    __shared__ int ws[4];
    int t = threadIdx.x, lane = t & 63, w = t >> 6;
    int idx = blockIdx.x * 256 + t;
    int v = (idx < n) ? deg[idx] : 0;
    if (idx < n) dinv[idx] = rsqrtf((float)(v + 1));  // +1 self-loop
    int r = v;
    #pragma unroll
    for (int off = 32; off > 0; off >>= 1) r += __shfl_down(r, off, 64);
    if (lane == 0) ws[w] = r;
    __syncthreads();
    if (t == 0) bsum[blockIdx.x] = ws[0] + ws[1] + ws[2] + ws[3];
}

// ---- apply with self-computed block offset ------------------------------
__launch_bounds__(256)
__global__ void k_bapply2(const int* __restrict__ deg, const int* __restrict__ bsum,
                          int* __restrict__ row_ptr, int* __restrict__ cursor,
                          int n, int nb) {
    __shared__ int wred[4];
    __shared__ int wsum[4];
    __shared__ int boffs;
    int b = blockIdx.x, t = threadIdx.x, lane = t & 63, w = t >> 6;

    int pv = (t < b && t < nb) ? bsum[t] : 0;
    #pragma unroll
    for (int off = 32; off > 0; off >>= 1) pv += __shfl_down(pv, off, 64);
    if (lane == 0) wred[w] = pv;
    __syncthreads();
    if (t == 0) boffs = wred[0] + wred[1] + wred[2] + wred[3];
    __syncthreads();

    int idx = b * 256 + t;
    int v = (idx < n) ? deg[idx] : 0;
    int s = v;
    #pragma unroll
    for (int off = 1; off < 64; off <<= 1) {
        int x = __shfl_up(s, off, 64);
        if (lane >= off) s += x;
    }
    if (lane == 63) wsum[w] = s;
    __syncthreads();
    if (t == 0) {
        int acc = 0;
        #pragma unroll
        for (int i = 0; i < 4; i++) { int x = wsum[i]; wsum[i] = acc; acc += x; }
    }
    __syncthreads();
    int ex = boffs + s - v + wsum[w];
    if (idx < n) {
        row_ptr[idx] = ex;
        cursor[idx]  = ex;
    }
    if (idx == n - 1) row_ptr[n] = ex + v;
}

// ---- partitioned scatter ------------------------------------------------
__launch_bounds__(256)
__global__ void k_scatp(const int* __restrict__ dstb, const int* __restrict__ srcb,
                        const int* __restrict__ bcnt,
                        int* __restrict__ cursor, int* __restrict__ col, int E) {
    int p = blockIdx.x & 7;
    int nb = gridDim.x >> 3;
    int cnt = bcnt[p]; if (cnt > CAP) cnt = CAP;
    const int* db = dstb + p * CAP;
    const int* sb = srcb + p * CAP;
    for (int i = (blockIdx.x >> 3) * 256 + threadIdx.x; i < cnt; i += nb * 256) {
        int pos = atomicAdd(&cursor[db[i]], 1);
        if ((unsigned)pos < (unsigned)E) col[pos] = sb[i];
    }
}

// ---- Split-K pull aggregation -------------------------------------------
// 4 waves = 2 nodes x 2 half-lists; dinv applied per-edge (hs unscaled).
// act = relu(dinv[d]*(sum dinv[s]*h[s] + dinv[d]*h[d]) + b)
__launch_bounds__(256)
__global__ void k_agg(const unsigned short* __restrict__ hsv,
                      const int* __restrict__ row_ptr,
                      const int* __restrict__ col, const float* __restrict__ dinv,
                      const float* __restrict__ bias,
                      unsigned short* __restrict__ out8, float* __restrict__ partial,
                      int n, int E) {
    __shared__ float pl[4][128];
    int w = threadIdx.x >> 6;
    int lane = threadIdx.x & 63;
    int node = blockIdx.x * 2 + (w >> 1);
    int half = w & 1;
    bool active = (node < n);
    int nd = active ? node : 0;

    int start = row_ptr[nd];
    int end = active ? row_ptr[nd + 1] : start;
    if (start < 0) start = 0;
    if (end > E) end = E;
    int len = end - start;
    if (len < 0) len = 0;
    int len1 = ((len >> 1) + 7) & ~7;
    if (len1 > len) len1 = len;

    float a0, a1;
    int e, hend;
    if (half == 0) {
        float dnd = dinv[nd];
        f32x2 sf = __builtin_amdgcn_cvt_pk_f32_fp8((int)hsv[nd * 64 + lane], false);
        a0 = dnd * sf.x; a1 = dnd * sf.y;
        e = start; hend = start + len1;
    } else {
        a0 = 0.f; a1 = 0.f;
        e = start + len1; hend = end;
    }

    for (; e + 8 <= hend; e += 8) {
        unsigned s0 = (unsigned)col[e],     s1 = (unsigned)col[e + 1];
        unsigned s2 = (unsigned)col[e + 2], s3 = (unsigned)col[e + 3];
        unsigned s4 = (unsigned)col[e + 4], s5 = (unsigned)col[e + 5];
        unsigned s6 = (unsigned)col[e + 6], s7 = (unsigned)col[e + 7];
        if (s0 >= (unsigned)n) s0 = 0;
        if (s1 >= (unsigned)n) s1 = 0;
        if (s2 >= (unsigned)n) s2 = 0;
        if (s3 >= (unsigned)n) s3 = 0;
        if (s4 >= (unsigned)n) s4 = 0;
        if (s5 >= (unsigned)n) s5 = 0;
        if (s6 >= (unsigned)n) s6 = 0;
        if (s7 >= (unsigned)n) s7 = 0;
        float d0 = dinv[s0], d1 = dinv[s1], d2 = dinv[s2], d3 = dinv[s3];
        float d4 = dinv[s4], d5 = dinv[s5], d6 = dinv[s6], d7 = dinv[s7];
        int u0 = hsv[s0 * 64 + lane];
        int u1 = hsv[s1 * 64 + lane];
        int u2 = hsv[s2 * 64 + lane];
        int u3 = hsv[s3 * 64 + lane];
        int u4 = hsv[s4 * 64 + lane];
        int u5 = hsv[s5 * 64 + lane];
        int u6 = hsv[s6 * 64 + lane];
        int u7 = hsv[s7 * 64 + lane];
        f32x2 f0 = __builtin_amdgcn_cvt_pk_f32_fp8(u0, false);
        f32x2 f1 = __builtin_amdgcn_cvt_pk_f32_fp8(u1, false);
        f32x2 f2 = __builtin_amdgcn_cvt_pk_f32_fp8(u2, false);
        f32x2 f3 = __builtin_amdgcn_cvt_pk_f32_fp8(u3, false);
        f32x2 f4 = __builtin_amdgcn_cvt_pk_f32_fp8(u4, false);
        f32x2 f5 = __builtin_amdgcn_cvt_pk_f32_fp8(u5, false);
        f32x2 f6 = __builtin_amdgcn_cvt_pk_f32_fp8(u6, false);
        f32x2 f7 = __builtin_amdgcn_cvt_pk_f32_fp8(u7, false);
        a0 += d0 * f0.x + d1 * f1.x + d2 * f2.x + d3 * f3.x
            + d4 * f4.x + d5 * f5.x + d6 * f6.x + d7 * f7.x;
        a1 += d0 * f0.y + d1 * f1.y + d2 * f2.y + d3 * f3.y
            + d4 * f4.y + d5 * f5.y + d6 * f6.y + d7 * f7.y;
    }
    for (; e < hend; ++e) {
        unsigned s0 = (unsigned)col[e];
        if (s0 >= (unsigned)n) s0 = 0;
        float d0 = dinv[s0];
        f32x2 f = __builtin_amdgcn_cvt_pk_f32_fp8((int)hsv[s0 * 64 + lane], false);
        a0 += d0 * f.x;
        a1 += d0 * f.y;
    }

    pl[w][2 * lane]     = a0;
    pl[w][2 * lane + 1] = a1;
    __syncthreads();

    if (half == 0) {
        float c0 = pl[w][2 * lane]     + pl[w + 1][2 * lane];
        float c1 = pl[w][2 * lane + 1] + pl[w + 1][2 * lane + 1];
        float dv = dinv[nd];
        float2 bu = ((const float2*)bias)[lane];
        float r0 = fmaxf(dv * c0 + bu.x, 0.f);
        float r1 = fmaxf(dv * c1 + bu.y, 0.f);
        if (!active) { r0 = 0.f; r1 = 0.f; }
        if (out8 != nullptr && active) {
            int pk = __builtin_amdgcn_cvt_pk_fp8_f32(r0, r1, 0, false);
            out8[node * 64 + lane] = (unsigned short)(pk & 0xFFFF);
        }
        pl[w][2 * lane]     = r0;   // own row: safe after reads above
        pl[w][2 * lane + 1] = r1;
    }
    if (partial != nullptr) {
        __syncthreads();
        int t = threadIdx.x;
        if (t < 128) partial[blockIdx.x * 128 + t] = pl[0][t] + pl[2][t];
    }
}

// ---- fused pooled reduce + FC (last-block pattern) ----------------------
__launch_bounds__(256)
__global__ void k_redfinal(const float* __restrict__ partial, float* __restrict__ pooled,
                           int* __restrict__ done,
                           const float* __restrict__ Wfcf, const float* __restrict__ bfcf,
                           const void* __restrict__ x, void* __restrict__ out,
                           int n, int nbrows, int gblocks) {
    __shared__ float red[8][128];
    int t = threadIdx.x;
    int chunk = (nbrows + gblocks - 1) / gblocks;
    int r0 = blockIdx.x * chunk;
    int r1 = r0 + chunk;
    if (r1 > nbrows) r1 = nbrows;

    float4 acc = {0.f, 0.f, 0.f, 0.f};
    const float4* p4 = (const float4*)partial;
    for (int i = r0 * 32 + t; i < r1 * 32; i += 256) {
        float4 v = p4[i];
        acc.x += v.x; acc.y += v.y; acc.z += v.z; acc.w += v.w;
    }
    int g = t >> 5;
    int fb = (t & 31) * 4;
    red[g][fb]     = acc.x;
    red[g][fb + 1] = acc.y;
    red[g][fb + 2] = acc.z;
    red[g][fb + 3] = acc.w;
    __syncthreads();
    if (t < 128) {
        float s = red[0][t] + red[1][t] + red[2][t] + red[3][t]
                + red[4][t] + red[5][t] + red[6][t] + red[7][t];
        atomicAdd(&pooled[t], s);
    }
    __threadfence();
    __shared__ int lastf;
    if (t == 0) lastf = (atomicAdd(done, 1) == gblocks - 1) ? 1 : 0;
    __syncthreads();
    if (!lastf) return;

    __shared__ int hits;
    __shared__ float pv[128];
    if (t == 0) hits = 0;
    __syncthreads();
    unsigned ew = (((const uint32_t*)x)[t] >> 7) & 0xFFu;
    unsigned long long bl = __ballot(ew >= 0x60u && ew <= 0x90u);
    if ((t & 63) == 0) atomicAdd(&hits, (int)__popcll(bl));
    if (t < 128)
        pv[t] = __hip_atomic_load(&pooled[t], __ATOMIC_RELAXED,
                                  __HIP_MEMORY_SCOPE_AGENT);
    __syncthreads();
    int isbf = (2 * hits > 256);
    if (t < 32) {
        float s = 0.f;
        for (int c = 0; c < 128; ++c) s += pv[c] * Wfcf[c * 32 + t];
        s = s * (1.0f / (float)n) + bfcf[t];
        if (isbf) ((unsigned short*)out)[t] = f2bf(s);
        else      ((float*)out)[t] = s;
    }
}

// ---- Launch -------------------------------------------------------------

extern "C" void kernel_launch(void* const* d_in, const int* in_sizes, int n_in,
                              void* d_out, int out_size, void* d_ws, size_t ws_size,
                              hipStream_t stream) {
    const void* x   = d_in[0];
    const int*  ei  = (const int*)d_in[1];
    const void* W1  = d_in[2];
    const void* b1  = d_in[3];
    const void* W2  = d_in[4];
    const void* b2  = d_in[5];
    const void* Wfc = d_in[6];
    const void* bfc = d_in[7];

    const int n = in_sizes[0] / FEAT;    // 50000
    const int E = in_sizes[1] / 2;       // 800000
    const int nagg2 = (n + 1) / 2;       // 25000 (2 nodes/block)
    const int psz  = (n + 7) / 8;        // 6250
    const int nscan = (n + 255) / 256;   // 196
    const int NE   = (E + ECH - 1) / ECH;// 391
    const int gemm_grid = ((n + 15) / 16 + 3) / 4;  // 782

    char* ws = (char*)d_ws;
    uint32_t*       hs8     = (uint32_t*)(ws);                     // 6.4MB used
    unsigned short* act8    = (unsigned short*)(ws + 12800000);    // 6.4MB (act1 fp8)
    float*          partial = (float*)(ws + 25600000);             // 12.8MB (25000x128)
    int*            col     = (int*)(ws + 38400000);               // 3.2MB
    int*            dstb    = (int*)(ws + 41600000);               // 6.4MB (8*CAP)
    int*            srcb    = (int*)(ws + 48000000);               // 6.4MB
    int*            deg     = (int*)(ws + 54400000);               // 200,000
    int*            row_ptr = (int*)(ws + 54600000);               // 200,016
    int*            cursor  = (int*)(ws + 54800016);               // 200,000
    float*          dinv    = (float*)(ws + 55000016);             // 200,000
    unsigned short* Wth1    = (unsigned short*)(ws + 55200016);    // 32,768
    unsigned short* Wth2    = (unsigned short*)(ws + 55232784);    // 32,768
    float*          b1f     = (float*)(ws + 55265552);             // 512
    float*          b2f     = (float*)(ws + 55266064);             // 512
    float*          Wfcf    = (float*)(ws + 55266576);             // 16,384
    float*          bfcf    = (float*)(ws + 55282960);             // 128
    // zero region (one memset): pooled | bcnt | done(+pad) | bsum
    float*          pooled  = (float*)(ws + 55283088);             // 512
    int*            bcnt    = (int*)(ws + 55283600);               // 32
    int*            done    = (int*)(ws + 55283632);               // 4 (+12 pad)
    int*            bsum    = (int*)(ws + 55283648);               // 784

    if (ws_size < 55284448) return;  // diagnostic: zero output => ws too small

    hipMemsetAsync(pooled, 0, 1344, stream);

    // 1) fused prep: edge decode+bucket (+deg zero) | weight/bias prep
    k_prep<<<NE + 82, 256, 0, stream>>>(ei, dstb, srcb, bcnt, deg, E, n, psz, NE,
                                        W1, W2, b1, b2, Wfc, bfc,
                                        Wth1, Wth2, b1f, b2f, Wfcf, bfcf);
    // 2) fused: degree count || GEMM layer-1 (hs unscaled => no dinv dep)
    k_dg<<<DEGB + gemm_grid, 256, 0, stream>>>(dstb, bcnt, deg, x, Wth1, hs8, n);
    // 3) scan (2 dispatches; grid barriers measured ~80us each on gfx950 - R11)
    k_bsum<<<nscan, 256, 0, stream>>>(deg, bsum, dinv, n);
    k_bapply2<<<nscan, 256, 0, stream>>>(deg, bsum, row_ptr, cursor, n, nscan);
    // 4) scatter
    k_scatp<<<512, 256, 0, stream>>>(dstb, srcb, bcnt, cursor, col, E);

    // layer 1 aggregation (split-K, dinv applied per-edge)
    k_agg<<<nagg2, 256, 0, stream>>>((const unsigned short*)hs8, row_ptr, col, dinv,
                                     b1f, act8, nullptr, n, E);
    // layer 2
    k_gemm<<<gemm_grid, 256, 0, stream>>>(act8, Wth2, hs8, n, 2);
    k_agg<<<nagg2, 256, 0, stream>>>((const unsigned short*)hs8, row_ptr, col, dinv,
                                     b2f, nullptr, partial, n, E);
    // fused pooled-reduce + FC
    k_redfinal<<<100, 256, 0, stream>>>(partial, pooled, done, Wfcf, bfcf,
                                        x, d_out, n, nagg2, 100);
}

// Round 15
// 297.101 us; speedup vs baseline: 1.0931x; 1.0931x over previous
//
#include <hip/hip_runtime.h>
#include <stdint.h>

#define FEAT 128
#define ECH 2048   // edges per econv block
#define CAP 200000 // per-partition edge capacity

typedef short bf16x8 __attribute__((ext_vector_type(8)));
typedef float f32x4 __attribute__((ext_vector_type(4)));
typedef float f32x2 __attribute__((ext_vector_type(2)));

__device__ __forceinline__ float bfs(unsigned short u) {
    uint32_t t = ((uint32_t)u) << 16;
    return __builtin_bit_cast(float, t);
}
__device__ __forceinline__ unsigned short f2bf(float f) {
    uint32_t u = __builtin_bit_cast(uint32_t, f);
    u += 0x7fffu + ((u >> 16) & 1u);
    return (unsigned short)(u >> 16);
}

// ---- fused prep: econv blocks [0,NE) | W blocks [NE,NE+64) | bias [+18) -
__launch_bounds__(256)
__global__ void k_prep(const int* __restrict__ ei,
                       int* __restrict__ dstb, int* __restrict__ srcb,
                       int* __restrict__ bcnt, int* __restrict__ deg,
                       int E, int n, int psz, int NE,
                       const void* W1, const void* W2,
                       const void* b1, const void* b2,
                       const void* Wfc, const void* bfc,
                       unsigned short* Wth1, unsigned short* Wth2,
                       float* b1f, float* b2f, float* Wfcf, float* bfcf) {
    int t = threadIdx.x;

    if ((int)blockIdx.x >= NE) {
        // ---- weight/bias prep ----
        __shared__ int hits;
        int blk = blockIdx.x - NE;
        const void* sampsrc = (blk < 32) ? W1 : (blk < 64 ? W2 : Wfc);
        const uint32_t* samp = (const uint32_t*)sampsrc;
        if (t == 0) hits = 0;
        __syncthreads();
        unsigned ew = (samp[t] >> 7) & 0xFFu;
        unsigned long long bl = __ballot(ew >= 0x60u && ew <= 0x90u);
        if ((t & 63) == 0) atomicAdd(&hits, (int)__popcll(bl));
        __syncthreads();
        int isbf = (2 * hits > 256);

        if (blk < 64) {
            // transpose W (128x128) -> Wth[nout][k], bf16; 2 elems/thread
            const void* W = (blk < 32) ? W1 : W2;
            unsigned short* th = (blk < 32) ? Wth1 : Wth2;
            int base = (blk & 31) * 512;
            #pragma unroll
            for (int j = 0; j < 2; j++) {
                int idx = base + t * 2 + j;
                int nn = idx >> 7, k = idx & 127;
                int si = k * 128 + nn;
                float f = isbf ? bfs(((const unsigned short*)W)[si])
                               : ((const float*)W)[si];
                th[nn * 128 + k] = f2bf(f);
            }
        } else {
            int i = (blk - 64) * 256 + t;
            if (i >= 4384) return;
            const void* src; float* dst; int off;
            if (i < 128)       { src = b1;  dst = b1f;  off = i; }
            else if (i < 256)  { src = b2;  dst = b2f;  off = i - 128; }
            else if (i < 4352) { src = Wfc; dst = Wfcf; off = i - 256; }
            else               { src = bfc; dst = bfcf; off = i - 4352; }
            dst[off] = isbf ? bfs(((const unsigned short*)src)[off])
                            : ((const float*)src)[off];
        }
        return;
    }

    // ---- econv part (+ zero its deg slice) ----
    __shared__ int lflag;
    __shared__ int cnt[8], lofs[8], gbase[8];
    __shared__ int stage_s[ECH];
    __shared__ int stage_d[ECH];
    __shared__ char sb[ECH];
    if (t < 128) {
        int di = blockIdx.x * 128 + t;
        if (di < n) deg[di] = 0;
    }
    if (t == 0) lflag = 0;
    if (t < 8) cnt[t] = 0;
    __syncthreads();
    if (ei[1 + 2 * t] != 0) atomicOr(&lflag, 1);   // odd words: 0 => int64
    __syncthreads();
    int is32 = lflag;

    int base = blockIdx.x * ECH;
    int s[8], d[8], p[8], slot[8];
    #pragma unroll
    for (int j = 0; j < 8; j++) {
        int e = base + j * 256 + t;
        int ss = 0, dd = 0;
        if (e < E) {
            ss = is32 ? ei[e]     : ei[2 * e];
            dd = is32 ? ei[E + e] : ei[2 * E + 2 * e];
            if ((unsigned)ss >= (unsigned)n) ss = 0;
            if ((unsigned)dd >= (unsigned)n) dd = 0;
            int pp = dd / psz;
            if (pp > 7) pp = 7;
            p[j] = pp;
            slot[j] = atomicAdd(&cnt[pp], 1);
        } else p[j] = -1;
        s[j] = ss; d[j] = dd;
    }
    __syncthreads();
    if (t == 0) {
        int acc = 0;
        #pragma unroll
        for (int i = 0; i < 8; i++) { lofs[i] = acc; acc += cnt[i]; }
    }
    __syncthreads();
    if (t < 8) gbase[t] = atomicAdd(&bcnt[t], cnt[t]);
    __syncthreads();
    #pragma unroll
    for (int j = 0; j < 8; j++) {
        if (p[j] >= 0) {
            int pos = lofs[p[j]] + slot[j];
            stage_s[pos] = s[j];
            stage_d[pos] = d[j];
            sb[pos] = (char)p[j];
        }
    }
    __syncthreads();
    int tot = lofs[7] + cnt[7];
    for (int i = t; i < tot; i += 256) {
        int pp = sb[i];
        int off = gbase[pp] + (i - lofs[pp]);
        if (off < CAP) {
            dstb[pp * CAP + off] = stage_d[i];
            srcb[pp * CAP + off] = stage_s[i];
        }
    }
}

// ---- partitioned degree count (dst-only read) ---------------------------
__launch_bounds__(256)
__global__ void k_degp(const int* __restrict__ dstb, const int* __restrict__ bcnt,
                       int* __restrict__ deg) {
    int p = blockIdx.x & 7;
    int nb = gridDim.x >> 3;
    int cnt = bcnt[p]; if (cnt > CAP) cnt = CAP;
    const int* db = dstb + p * CAP;
    for (int i = (blockIdx.x >> 3) * 256 + threadIdx.x; i < cnt; i += nb * 256)
        atomicAdd(&deg[db[i]], 1);
}

// ---- block sums (+ fused dinv) ------------------------------------------
__global__ void k_bsum(const int* __restrict__ deg, int* __restrict__ bsum,
                       float* __restrict__ dinv, int n) {
    __shared__ int ws[4];
    int t = threadIdx.x, lane = t & 63, w = t >> 6;
    int idx = blockIdx.x * 256 + t;
    int v = (idx < n) ? deg[idx] : 0;
    if (idx < n) dinv[idx] = rsqrtf((float)(v + 1));  // +1 self-loop
    int r = v;
    #pragma unroll
    for (int off = 32; off > 0; off >>= 1) r += __shfl_down(r, off, 64);
    if (lane == 0) ws[w] = r;
    __syncthreads();
    if (t == 0) bsum[blockIdx.x] = ws[0] + ws[1] + ws[2] + ws[3];
}

// ---- apply with self-computed block offset ------------------------------
__launch_bounds__(256)
__global__ void k_bapply2(const int* __restrict__ deg, const int* __restrict__ bsum,
                          int* __restrict__ row_ptr, int* __restrict__ cursor,
                          int n, int nb) {
    __shared__ int wred[4];
    __shared__ int wsum[4];
    __shared__ int boffs;
    int b = blockIdx.x, t = threadIdx.x, lane = t & 63, w = t >> 6;

    int pv = (t < b && t < nb) ? bsum[t] : 0;
    #pragma unroll
    for (int off = 32; off > 0; off >>= 1) pv += __shfl_down(pv, off, 64);
    if (lane == 0) wred[w] = pv;
    __syncthreads();
    if (t == 0) boffs = wred[0] + wred[1] + wred[2] + wred[3];
    __syncthreads();

    int idx = b * 256 + t;
    int v = (idx < n) ? deg[idx] : 0;
    int s = v;
    #pragma unroll
    for (int off = 1; off < 64; off <<= 1) {
        int x = __shfl_up(s, off, 64);
        if (lane >= off) s += x;
    }
    if (lane == 63) wsum[w] = s;
    __syncthreads();
    if (t == 0) {
        int acc = 0;
        #pragma unroll
        for (int i = 0; i < 4; i++) { int x = wsum[i]; wsum[i] = acc; acc += x; }
    }
    __syncthreads();
    int ex = boffs + s - v + wsum[w];
    if (idx < n) {
        row_ptr[idx] = ex;
        cursor[idx]  = ex;
    }
    if (idx == n - 1) row_ptr[n] = ex + v;
}

// ---- partitioned scatter ------------------------------------------------
__launch_bounds__(256)
__global__ void k_scatp(const int* __restrict__ dstb, const int* __restrict__ srcb,
                        const int* __restrict__ bcnt,
                        int* __restrict__ cursor, int* __restrict__ col, int E) {
    int p = blockIdx.x & 7;
    int nb = gridDim.x >> 3;
    int cnt = bcnt[p]; if (cnt > CAP) cnt = CAP;
    const int* db = dstb + p * CAP;
    const int* sb = srcb + p * CAP;
    for (int i = (blockIdx.x >> 3) * 256 + threadIdx.x; i < cnt; i += nb * 256) {
        int pos = atomicAdd(&cursor[db[i]], 1);
        if ((unsigned)pos < (unsigned)E) col[pos] = sb[i];
    }
}

// ---- GEMM: hs_fp8 = fp8(dinv[row] * (X @ W)), single-pass bf16 MFMA -----
// fmt 0: X = raw input (f32 or bf16, per-wave sample); fmt 2: X = fp8 act.
__launch_bounds__(256)
__global__ void k_gemm(const void* __restrict__ X,
                       const unsigned short* __restrict__ Wth,
                       const float* __restrict__ dinv,
                       uint32_t* __restrict__ hs8, int n, int fmt) {
    __shared__ unsigned char lds8[4][16 * 128];
    int wave = threadIdx.x >> 6;
    int l = threadIdx.x & 63;
    int quad = l >> 4;
    int m16 = l & 15;
    int r0 = (blockIdx.x * 4 + wave) * 16;

    int isbf;
    if (fmt != 0) isbf = 1;
    else {
        unsigned ew = (((const uint32_t*)X)[l] >> 7) & 0xFFu;
        unsigned long long bl = __ballot(ew >= 0x60u && ew <= 0x90u);
        isbf = ((int)__popcll(bl) * 2 > 64) ? 1 : 0;
    }

    int ra = r0 + m16;
    if (ra > n - 1) ra = n - 1;
    bf16x8 ah[4];
    if (fmt == 2) {
        const uint2* Xq = (const uint2*)X;   // 16 uint2 per 128-B fp8 row
        #pragma unroll
        for (int kt = 0; kt < 4; kt++) {
            uint2 v8 = Xq[ra * 16 + kt * 4 + quad];
            f32x2 p0 = __builtin_amdgcn_cvt_pk_f32_fp8((int)v8.x, false);
            f32x2 p1 = __builtin_amdgcn_cvt_pk_f32_fp8((int)v8.x, true);
            f32x2 p2 = __builtin_amdgcn_cvt_pk_f32_fp8((int)v8.y, false);
            f32x2 p3 = __builtin_amdgcn_cvt_pk_f32_fp8((int)v8.y, true);
            bf16x8 h;
            h[0] = (short)f2bf(p0.x); h[1] = (short)f2bf(p0.y);
            h[2] = (short)f2bf(p1.x); h[3] = (short)f2bf(p1.y);
            h[4] = (short)f2bf(p2.x); h[5] = (short)f2bf(p2.y);
            h[6] = (short)f2bf(p3.x); h[7] = (short)f2bf(p3.y);
            ah[kt] = h;
        }
    } else if (isbf) {
        const int4* Xv = (const int4*)X;
        #pragma unroll
        for (int kt = 0; kt < 4; kt++)
            ah[kt] = __builtin_bit_cast(bf16x8, Xv[ra * 16 + kt * 4 + quad]);
    } else {
        const float4* Xf = (const float4*)X;
        #pragma unroll
        for (int kt = 0; kt < 4; kt++) {
            int jj = kt * 4 + quad;
            float4 fa = Xf[ra * 32 + jj * 2];
            float4 fb = Xf[ra * 32 + jj * 2 + 1];
            float v[8] = {fa.x, fa.y, fa.z, fa.w, fb.x, fb.y, fb.z, fb.w};
            bf16x8 h;
            #pragma unroll
            for (int j = 0; j < 8; j++) h[j] = (short)f2bf(v[j]);
            ah[kt] = h;
        }
    }

    float dv[4];
    #pragma unroll
    for (int reg = 0; reg < 4; reg++) {
        int row = r0 + quad * 4 + reg;
        if (row > n - 1) row = n - 1;
        dv[reg] = dinv[row];
    }

    const int4* Wvh = (const int4*)Wth;
    #pragma unroll
    for (int nt = 0; nt < 8; nt++) {
        f32x4 acc = {0.f, 0.f, 0.f, 0.f};
        int brow = (nt * 16 + m16) * 16;
        #pragma unroll
        for (int kt = 0; kt < 4; kt++) {
            bf16x8 bh = __builtin_bit_cast(bf16x8, Wvh[brow + kt * 4 + quad]);
            acc = __builtin_amdgcn_mfma_f32_16x16x32_bf16(ah[kt], bh, acc, 0, 0, 0);
        }
        #pragma unroll
        for (int reg = 0; reg < 4; reg++) {
            float v = acc[reg] * dv[reg];
            int pk = __builtin_amdgcn_cvt_pk_fp8_f32(v, v, 0, false);
            lds8[wave][(quad * 4 + reg) * 128 + nt * 16 + m16] = (unsigned char)(pk & 0xFF);
        }
    }
    __syncthreads();
    const uint32_t* l32 = (const uint32_t*)lds8[wave];
    #pragma unroll
    for (int i = 0; i < 8; i++) {
        int idx = i * 64 + l;
        int row = idx >> 5;
        int grow = r0 + row;
        if (grow < n) hs8[grow * 32 + (idx & 31)] = l32[idx];
    }
}

// ---- Pull aggregation (fp8 hs, pre-scaled): 16-wide gather unroll -------
// act = relu(dinv[d]*(hs[d] + sum hs[s]) + b)
__launch_bounds__(256)
__global__ void k_agg(const unsigned short* __restrict__ hsv,
                      const int* __restrict__ row_ptr,
                      const int* __restrict__ col, const float* __restrict__ dinv,
                      const float* __restrict__ bias,
                      unsigned short* __restrict__ out8, float* __restrict__ partial,
                      int n, int E) {
    __shared__ float pl[4][128];
    int wave = threadIdx.x >> 6;
    int lane = threadIdx.x & 63;
    int node = blockIdx.x * 4 + wave;
    bool active = (node < n);
    int nd = active ? node : 0;

    f32x2 sf = __builtin_amdgcn_cvt_pk_f32_fp8((int)hsv[nd * 64 + lane], false);
    float a0 = sf.x, a1 = sf.y;

    int e = row_ptr[nd];
    int end = active ? row_ptr[nd + 1] : e;
    if (e < 0) e = 0;
    if (end > E) end = E;

    // 16 outstanding row-loads per round (avg deg ~16 -> one latency round)
    for (; e + 16 <= end; e += 16) {
        unsigned si[16];
        #pragma unroll
        for (int j = 0; j < 16; j++) {
            unsigned s = (unsigned)col[e + j];
            si[j] = (s < (unsigned)n) ? s : 0u;
        }
        int uu[16];
        #pragma unroll
        for (int j = 0; j < 16; j++) uu[j] = hsv[si[j] * 64 + lane];
        #pragma unroll
        for (int j = 0; j < 16; j++) {
            f32x2 f = __builtin_amdgcn_cvt_pk_f32_fp8(uu[j], false);
            a0 += f.x;
            a1 += f.y;
        }
    }
    for (; e + 8 <= end; e += 8) {
        unsigned si[8];
        #pragma unroll
        for (int j = 0; j < 8; j++) {
            unsigned s = (unsigned)col[e + j];
            si[j] = (s < (unsigned)n) ? s : 0u;
        }
        int uu[8];
        #pragma unroll
        for (int j = 0; j < 8; j++) uu[j] = hsv[si[j] * 64 + lane];
        #pragma unroll
        for (int j = 0; j < 8; j++) {
            f32x2 f = __builtin_amdgcn_cvt_pk_f32_fp8(uu[j], false);
            a0 += f.x;
            a1 += f.y;
        }
    }
    for (; e < end; ++e) {
        unsigned s0 = (unsigned)col[e];
        if (s0 >= (unsigned)n) s0 = 0;
        f32x2 f = __builtin_amdgcn_cvt_pk_f32_fp8((int)hsv[s0 * 64 + lane], false);
        a0 += f.x;
        a1 += f.y;
    }

    float dv = dinv[nd];
    float2 bu = ((const float2*)bias)[lane];
    float r0 = fmaxf(dv * a0 + bu.x, 0.f);
    float r1 = fmaxf(dv * a1 + bu.y, 0.f);
    if (!active) { r0 = 0.f; r1 = 0.f; }

    if (out8 != nullptr && active) {
        int pk = __builtin_amdgcn_cvt_pk_fp8_f32(r0, r1, 0, false);
        out8[node * 64 + lane] = (unsigned short)(pk & 0xFFFF);
    }
    if (partial != nullptr) {
        pl[wave][2 * lane]     = r0;
        pl[wave][2 * lane + 1] = r1;
        __syncthreads();
        int t = threadIdx.x;
        if (t < 128) {
            float ps = pl[0][t] + pl[1][t] + pl[2][t] + pl[3][t];
            partial[blockIdx.x * 128 + t] = ps;
        }
    }
}

// ---- fused pooled reduce + FC (last-block pattern) ----------------------
__launch_bounds__(256)
__global__ void k_redfinal(const float* __restrict__ partial, float* __restrict__ pooled,
                           int* __restrict__ done,
                           const float* __restrict__ Wfcf, const float* __restrict__ bfcf,
                           const void* __restrict__ x, void* __restrict__ out,
                           int n, int nbrows, int gblocks) {
    __shared__ float red[8][128];
    int t = threadIdx.x;
    int chunk = (nbrows + gblocks - 1) / gblocks;
    int r0 = blockIdx.x * chunk;
    int r1 = r0 + chunk;
    if (r1 > nbrows) r1 = nbrows;

    float4 acc = {0.f, 0.f, 0.f, 0.f};
    const float4* p4 = (const float4*)partial;
    for (int i = r0 * 32 + t; i < r1 * 32; i += 256) {
        float4 v = p4[i];
        acc.x += v.x; acc.y += v.y; acc.z += v.z; acc.w += v.w;
    }
    int g = t >> 5;
    int fb = (t & 31) * 4;
    red[g][fb]     = acc.x;
    red[g][fb + 1] = acc.y;
    red[g][fb + 2] = acc.z;
    red[g][fb + 3] = acc.w;
    __syncthreads();
    if (t < 128) {
        float s = red[0][t] + red[1][t] + red[2][t] + red[3][t]
                + red[4][t] + red[5][t] + red[6][t] + red[7][t];
        atomicAdd(&pooled[t], s);
    }
    __threadfence();
    __shared__ int lastf;
    if (t == 0) lastf = (atomicAdd(done, 1) == gblocks - 1) ? 1 : 0;
    __syncthreads();
    if (!lastf) return;

    __shared__ int hits;
    __shared__ float pv[128];
    if (t == 0) hits = 0;
    __syncthreads();
    unsigned ew = (((const uint32_t*)x)[t] >> 7) & 0xFFu;
    unsigned long long bl = __ballot(ew >= 0x60u && ew <= 0x90u);
    if ((t & 63) == 0) atomicAdd(&hits, (int)__popcll(bl));
    if (t < 128)
        pv[t] = __hip_atomic_load(&pooled[t], __ATOMIC_RELAXED,
                                  __HIP_MEMORY_SCOPE_AGENT);
    __syncthreads();
    int isbf = (2 * hits > 256);
    if (t < 32) {
        float s = 0.f;
        for (int c = 0; c < 128; ++c) s += pv[c] * Wfcf[c * 32 + t];
        s = s * (1.0f / (float)n) + bfcf[t];
        if (isbf) ((unsigned short*)out)[t] = f2bf(s);
        else      ((float*)out)[t] = s;
    }
}

// ---- Launch -------------------------------------------------------------

extern "C" void kernel_launch(void* const* d_in, const int* in_sizes, int n_in,
                              void* d_out, int out_size, void* d_ws, size_t ws_size,
                              hipStream_t stream) {
    const void* x   = d_in[0];
    const int*  ei  = (const int*)d_in[1];
    const void* W1  = d_in[2];
    const void* b1  = d_in[3];
    const void* W2  = d_in[4];
    const void* b2  = d_in[5];
    const void* Wfc = d_in[6];
    const void* bfc = d_in[7];

    const int n = in_sizes[0] / FEAT;    // 50000
    const int E = in_sizes[1] / 2;       // 800000
    const int nagg = (n + 3) / 4;        // 12500
    const int psz  = (n + 7) / 8;        // 6250
    const int nscan = (n + 255) / 256;   // 196
    const int NE   = (E + ECH - 1) / ECH;// 391

    char* ws = (char*)d_ws;
    uint32_t*       hs8     = (uint32_t*)(ws);                     // 6.4MB used
    unsigned short* act8    = (unsigned short*)(ws + 12800000);    // 6.4MB (act1 fp8)
    float*          partial = (float*)(ws + 25600000);             // 6.4MB used
    int*            col     = (int*)(ws + 38400000);               // 3.2MB
    int*            dstb    = (int*)(ws + 41600000);               // 6.4MB (8*CAP)
    int*            srcb    = (int*)(ws + 48000000);               // 6.4MB
    int*            deg     = (int*)(ws + 54400000);               // 200,000
    int*            row_ptr = (int*)(ws + 54600000);               // 200,016
    int*            cursor  = (int*)(ws + 54800016);               // 200,000
    float*          dinv    = (float*)(ws + 55000016);             // 200,000
    unsigned short* Wth1    = (unsigned short*)(ws + 55200016);    // 32,768
    unsigned short* Wth2    = (unsigned short*)(ws + 55232784);    // 32,768
    float*          b1f     = (float*)(ws + 55265552);             // 512
    float*          b2f     = (float*)(ws + 55266064);             // 512
    float*          Wfcf    = (float*)(ws + 55266576);             // 16,384
    float*          bfcf    = (float*)(ws + 55282960);             // 128
    // zero region (one memset): pooled | bcnt | done(+pad) | bsum
    float*          pooled  = (float*)(ws + 55283088);             // 512
    int*            bcnt    = (int*)(ws + 55283600);               // 32
    int*            done    = (int*)(ws + 55283632);               // 4 (+12 pad)
    int*            bsum    = (int*)(ws + 55283648);               // 784

    if (ws_size < 55284448) return;  // diagnostic: zero output => ws too small

    hipMemsetAsync(pooled, 0, 1344, stream);

    // 1) fused prep: edge decode+bucket (+deg zero) | weight/bias prep
    k_prep<<<NE + 82, 256, 0, stream>>>(ei, dstb, srcb, bcnt, deg, E, n, psz, NE,
                                        W1, W2, b1, b2, Wfc, bfc,
                                        Wth1, Wth2, b1f, b2f, Wfcf, bfcf);
    // 2) CSR build: 4 dispatches (dispatch boundary ~2us; grid barriers
    //    measured ~80us each on gfx950 -- R11)
    k_degp<<<512, 256, 0, stream>>>(dstb, bcnt, deg);
    k_bsum<<<nscan, 256, 0, stream>>>(deg, bsum, dinv, n);
    k_bapply2<<<nscan, 256, 0, stream>>>(deg, bsum, row_ptr, cursor, n, nscan);
    k_scatp<<<512, 256, 0, stream>>>(dstb, srcb, bcnt, cursor, col, E);

    int gemm_grid = (n + 63) / 64;   // 4 tiles of 16 rows per block
    // layer 1 (reads x directly, f32/bf16 auto; hs pre-scaled by dinv[row])
    k_gemm<<<gemm_grid, 256, 0, stream>>>(x, Wth1, dinv, hs8, n, 0);
    k_agg<<<nagg, 256, 0, stream>>>((const unsigned short*)hs8, row_ptr, col, dinv,
                                    b1f, act8, nullptr, n, E);
    // layer 2 (act fp8 -> in-register bf16)
    k_gemm<<<gemm_grid, 256, 0, stream>>>(act8, Wth2, dinv, hs8, n, 2);
    k_agg<<<nagg, 256, 0, stream>>>((const unsigned short*)hs8, row_ptr, col, dinv,
                                    b2f, nullptr, partial, n, E);
    // fused pooled-reduce + FC
    k_redfinal<<<100, 256, 0, stream>>>(partial, pooled, done, Wfcf, bfcf,
                                        x, d_out, n, nagg, 100);
}

// Round 16
// 277.449 us; speedup vs baseline: 1.1706x; 1.0708x over previous
//
#include <hip/hip_runtime.h>
#include <stdint.h>

#define FEAT 128
#define ECH 2048   // edges per econv block
#define CAP 200000 // per-partition edge capacity
#define SCB 512    // scatter blocks in fused k_sg

typedef short bf16x8 __attribute__((ext_vector_type(8)));
typedef float f32x4 __attribute__((ext_vector_type(4)));
typedef float f32x2 __attribute__((ext_vector_type(2)));

__device__ __forceinline__ float bfs(unsigned short u) {
    uint32_t t = ((uint32_t)u) << 16;
    return __builtin_bit_cast(float, t);
}
__device__ __forceinline__ unsigned short f2bf(float f) {
    uint32_t u = __builtin_bit_cast(uint32_t, f);
    u += 0x7fffu + ((u >> 16) & 1u);
    return (unsigned short)(u >> 16);
}

// ---- fused prep: econv blocks [0,NE) | W blocks [NE,NE+64) | bias [+18) -
__launch_bounds__(256)
__global__ void k_prep(const int* __restrict__ ei,
                       int* __restrict__ dstb, int* __restrict__ srcb,
                       int* __restrict__ bcnt, int* __restrict__ deg,
                       int E, int n, int psz, int NE,
                       const void* W1, const void* W2,
                       const void* b1, const void* b2,
                       const void* Wfc, const void* bfc,
                       unsigned short* Wth1, unsigned short* Wth2,
                       float* b1f, float* b2f, float* Wfcf, float* bfcf) {
    int t = threadIdx.x;

    if ((int)blockIdx.x >= NE) {
        __shared__ int hits;
        int blk = blockIdx.x - NE;
        const void* sampsrc = (blk < 32) ? W1 : (blk < 64 ? W2 : Wfc);
        const uint32_t* samp = (const uint32_t*)sampsrc;
        if (t == 0) hits = 0;
        __syncthreads();
        unsigned ew = (samp[t] >> 7) & 0xFFu;
        unsigned long long bl = __ballot(ew >= 0x60u && ew <= 0x90u);
        if ((t & 63) == 0) atomicAdd(&hits, (int)__popcll(bl));
        __syncthreads();
        int isbf = (2 * hits > 256);

        if (blk < 64) {
            const void* W = (blk < 32) ? W1 : W2;
            unsigned short* th = (blk < 32) ? Wth1 : Wth2;
            int base = (blk & 31) * 512;
            #pragma unroll
            for (int j = 0; j < 2; j++) {
                int idx = base + t * 2 + j;
                int nn = idx >> 7, k = idx & 127;
                int si = k * 128 + nn;
                float f = isbf ? bfs(((const unsigned short*)W)[si])
                               : ((const float*)W)[si];
                th[nn * 128 + k] = f2bf(f);
            }
        } else {
            int i = (blk - 64) * 256 + t;
            if (i >= 4384) return;
            const void* src; float* dst; int off;
            if (i < 128)       { src = b1;  dst = b1f;  off = i; }
            else if (i < 256)  { src = b2;  dst = b2f;  off = i - 128; }
            else if (i < 4352) { src = Wfc; dst = Wfcf; off = i - 256; }
            else               { src = bfc; dst = bfcf; off = i - 4352; }
            dst[off] = isbf ? bfs(((const unsigned short*)src)[off])
                            : ((const float*)src)[off];
        }
        return;
    }

    // ---- econv part (+ zero its deg slice) ----
    __shared__ int lflag;
    __shared__ int cnt[8], lofs[8], gbase[8];
    __shared__ int stage_s[ECH];
    __shared__ int stage_d[ECH];
    __shared__ char sb[ECH];
    if (t < 128) {
        int di = blockIdx.x * 128 + t;
        if (di < n) deg[di] = 0;
    }
    if (t == 0) lflag = 0;
    if (t < 8) cnt[t] = 0;
    __syncthreads();
    if (ei[1 + 2 * t] != 0) atomicOr(&lflag, 1);   // odd words: 0 => int64
    __syncthreads();
    int is32 = lflag;

    int base = blockIdx.x * ECH;
    int s[8], d[8], p[8], slot[8];
    #pragma unroll
    for (int j = 0; j < 8; j++) {
        int e = base + j * 256 + t;
        int ss = 0, dd = 0;
        if (e < E) {
            ss = is32 ? ei[e]     : ei[2 * e];
            dd = is32 ? ei[E + e] : ei[2 * E + 2 * e];
            if ((unsigned)ss >= (unsigned)n) ss = 0;
            if ((unsigned)dd >= (unsigned)n) dd = 0;
            int pp = dd / psz;
            if (pp > 7) pp = 7;
            p[j] = pp;
            slot[j] = atomicAdd(&cnt[pp], 1);
        } else p[j] = -1;
        s[j] = ss; d[j] = dd;
    }
    __syncthreads();
    if (t == 0) {
        int acc = 0;
        #pragma unroll
        for (int i = 0; i < 8; i++) { lofs[i] = acc; acc += cnt[i]; }
    }
    __syncthreads();
    if (t < 8) gbase[t] = atomicAdd(&bcnt[t], cnt[t]);
    __syncthreads();
    #pragma unroll
    for (int j = 0; j < 8; j++) {
        if (p[j] >= 0) {
            int pos = lofs[p[j]] + slot[j];
            stage_s[pos] = s[j];
            stage_d[pos] = d[j];
            sb[pos] = (char)p[j];
        }
    }
    __syncthreads();
    int tot = lofs[7] + cnt[7];
    for (int i = t; i < tot; i += 256) {
        int pp = sb[i];
        int off = gbase[pp] + (i - lofs[pp]);
        if (off < CAP) {
            dstb[pp * CAP + off] = stage_d[i];
            srcb[pp * CAP + off] = stage_s[i];
        }
    }
}

// ---- partitioned degree count (dst-only read) ---------------------------
__launch_bounds__(256)
__global__ void k_degp(const int* __restrict__ dstb, const int* __restrict__ bcnt,
                       int* __restrict__ deg) {
    int p = blockIdx.x & 7;
    int nb = gridDim.x >> 3;
    int cnt = bcnt[p]; if (cnt > CAP) cnt = CAP;
    const int* db = dstb + p * CAP;
    for (int i = (blockIdx.x >> 3) * 256 + threadIdx.x; i < cnt; i += nb * 256)
        atomicAdd(&deg[db[i]], 1);
}

// ---- block sums (+ fused dinv) ------------------------------------------
__global__ void k_bsum(const int* __restrict__ deg, int* __restrict__ bsum,
                       float* __restrict__ dinv, int n) {
    __shared__ int ws[4];
    int t = threadIdx.x, lane = t & 63, w = t >> 6;
    int idx = blockIdx.x * 256 + t;
    int v = (idx < n) ? deg[idx] : 0;
    if (idx < n) dinv[idx] = rsqrtf((float)(v + 1));  // +1 self-loop
    int r = v;
    #pragma unroll
    for (int off = 32; off > 0; off >>= 1) r += __shfl_down(r, off, 64);
    if (lane == 0) ws[w] = r;
    __syncthreads();
    if (t == 0) bsum[blockIdx.x] = ws[0] + ws[1] + ws[2] + ws[3];
}

// ---- apply with self-computed block offset ------------------------------
__launch_bounds__(256)
__global__ void k_bapply2(const int* __restrict__ deg, const int* __restrict__ bsum,
                          int* __restrict__ row_ptr, int* __restrict__ cursor,
                          int n, int nb) {
    __shared__ int wred[4];
    __shared__ int wsum[4];
    __shared__ int boffs;
    int b = blockIdx.x, t = threadIdx.x, lane = t & 63, w = t >> 6;

    int pv = (t < b && t < nb) ? bsum[t] : 0;
    #pragma unroll
    for (int off = 32; off > 0; off >>= 1) pv += __shfl_down(pv, off, 64);
    if (lane == 0) wred[w] = pv;
    __syncthreads();
    if (t == 0) boffs = wred[0] + wred[1] + wred[2] + wred[3];
    __syncthreads();

    int idx = b * 256 + t;
    int v = (idx < n) ? deg[idx] : 0;
    int s = v;
    #pragma unroll
    for (int off = 1; off < 64; off <<= 1) {
        int x = __shfl_up(s, off, 64);
        if (lane >= off) s += x;
    }
    if (lane == 63) wsum[w] = s;
    __syncthreads();
    if (t == 0) {
        int acc = 0;
        #pragma unroll
        for (int i = 0; i < 4; i++) { int x = wsum[i]; wsum[i] = acc; acc += x; }
    }
    __syncthreads();
    int ex = boffs + s - v + wsum[w];
    if (idx < n) {
        row_ptr[idx] = ex;
        cursor[idx]  = ex;
    }
    if (idx == n - 1) row_ptr[n] = ex + v;
}

// ---- GEMM tile body: hs8 = fp8(dinv[row]*(X @ W)) -----------------------
__device__ __forceinline__ void gemm_body(const void* __restrict__ X,
                                          const unsigned short* __restrict__ Wth,
                                          const float* __restrict__ dinv,
                                          uint32_t* __restrict__ hs8,
                                          int n, int tile, int l,
                                          unsigned char* __restrict__ ldsrow) {
    int quad = l >> 4;
    int m16 = l & 15;
    int r0 = tile * 16;

    unsigned ew = (((const uint32_t*)X)[l] >> 7) & 0xFFu;
    unsigned long long bl = __ballot(ew >= 0x60u && ew <= 0x90u);
    int isbf = ((int)__popcll(bl) * 2 > 64) ? 1 : 0;

    int ra = r0 + m16;
    if (ra > n - 1) ra = n - 1;
    bf16x8 ah[4];
    if (isbf) {
        const int4* Xv = (const int4*)X;
        #pragma unroll
        for (int kt = 0; kt < 4; kt++)
            ah[kt] = __builtin_bit_cast(bf16x8, Xv[ra * 16 + kt * 4 + quad]);
    } else {
        const float4* Xf = (const float4*)X;
        #pragma unroll
        for (int kt = 0; kt < 4; kt++) {
            int jj = kt * 4 + quad;
            float4 fa = Xf[ra * 32 + jj * 2];
            float4 fb = Xf[ra * 32 + jj * 2 + 1];
            float v[8] = {fa.x, fa.y, fa.z, fa.w, fb.x, fb.y, fb.z, fb.w};
            bf16x8 h;
            #pragma unroll
            for (int j = 0; j < 8; j++) h[j] = (short)f2bf(v[j]);
            ah[kt] = h;
        }
    }

    float dv[4];
    #pragma unroll
    for (int reg = 0; reg < 4; reg++) {
        int row = r0 + quad * 4 + reg;
        if (row > n - 1) row = n - 1;
        dv[reg] = dinv[row];
    }

    const int4* Wvh = (const int4*)Wth;
    #pragma unroll
    for (int nt = 0; nt < 8; nt++) {
        f32x4 acc = {0.f, 0.f, 0.f, 0.f};
        int brow = (nt * 16 + m16) * 16;
        #pragma unroll
        for (int kt = 0; kt < 4; kt++) {
            bf16x8 bh = __builtin_bit_cast(bf16x8, Wvh[brow + kt * 4 + quad]);
            acc = __builtin_amdgcn_mfma_f32_16x16x32_bf16(ah[kt], bh, acc, 0, 0, 0);
        }
        #pragma unroll
        for (int reg = 0; reg < 4; reg++) {
            float v = acc[reg] * dv[reg];
            int pk = __builtin_amdgcn_cvt_pk_fp8_f32(v, v, 0, false);
            ldsrow[(quad * 4 + reg) * 128 + nt * 16 + m16] = (unsigned char)(pk & 0xFF);
        }
    }
    __syncthreads();
    const uint32_t* l32 = (const uint32_t*)ldsrow;
    #pragma unroll
    for (int i = 0; i < 8; i++) {
        int idx = i * 64 + l;
        int row = idx >> 5;
        int grow = r0 + row;
        if (grow < n) hs8[grow * 32 + (idx & 31)] = l32[idx];
    }
}

// ---- fused: scatter [0,SCB) || GEMM layer-1 [SCB,..) --------------------
__launch_bounds__(256)
__global__ void k_sg(const int* __restrict__ dstb, const int* __restrict__ srcb,
                     const int* __restrict__ bcnt,
                     int* __restrict__ cursor, int* __restrict__ col, int E,
                     const void* __restrict__ X,
                     const unsigned short* __restrict__ Wth,
                     const float* __restrict__ dinv,
                     uint32_t* __restrict__ hs8, int n) {
    __shared__ unsigned char lds8[4][16 * 128];
    int b = blockIdx.x;
    if (b < SCB) {
        int p = b & 7;
        int nb = SCB >> 3;
        int cnt = bcnt[p]; if (cnt > CAP) cnt = CAP;
        const int* db = dstb + p * CAP;
        const int* sb = srcb + p * CAP;
        for (int i = (b >> 3) * 256 + threadIdx.x; i < cnt; i += nb * 256) {
            int pos = atomicAdd(&cursor[db[i]], 1);
            if ((unsigned)pos < (unsigned)E) col[pos] = sb[i];
        }
        return;
    }
    int wave = threadIdx.x >> 6;
    int l = threadIdx.x & 63;
    gemm_body(X, Wth, dinv, hs8, n, (b - SCB) * 4 + wave, l, lds8[wave]);
}

// ---- fused agg-1 + GEMM-2: block owns 16 nodes --------------------------
// Phase A: 4 waves x 4 sequential nodes -> act rows (bf16) in padded LDS.
// Phase B: 16-row MFMA tile vs Wth2; each wave 2 nt-slices; fp8 pack+store.
__launch_bounds__(256)
__global__ void k_agg1gemm2(const unsigned short* __restrict__ hsv,
                            const int* __restrict__ row_ptr,
                            const int* __restrict__ col,
                            const float* __restrict__ dinv,
                            const float* __restrict__ bias,
                            const unsigned short* __restrict__ Wth2,
                            uint32_t* __restrict__ hs8out, int n, int E) {
    __shared__ unsigned short actlds[16 * 136];   // stride 136: bank-safe
    __shared__ unsigned char pack[16 * 128];
    int wave = threadIdx.x >> 6;
    int lane = threadIdx.x & 63;
    int tile0 = blockIdx.x * 16;

    // Phase A: aggregation (hs pre-scaled by dinv[src]; apply dinv[d]+bias+relu)
    for (int i = 0; i < 4; i++) {
        int node = tile0 + wave * 4 + i;
        bool active = (node < n);
        int nd = active ? node : 0;

        f32x2 sf = __builtin_amdgcn_cvt_pk_f32_fp8((int)hsv[nd * 64 + lane], false);
        float a0 = sf.x, a1 = sf.y;

        int e = row_ptr[nd];
        int end = active ? row_ptr[nd + 1] : e;
        if (e < 0) e = 0;
        if (end > E) end = E;

        for (; e + 8 <= end; e += 8) {
            unsigned si[8];
            #pragma unroll
            for (int j = 0; j < 8; j++) {
                unsigned s = (unsigned)col[e + j];
                si[j] = (s < (unsigned)n) ? s : 0u;
            }
            int uu[8];
            #pragma unroll
            for (int j = 0; j < 8; j++) uu[j] = hsv[si[j] * 64 + lane];
            #pragma unroll
            for (int j = 0; j < 8; j++) {
                f32x2 f = __builtin_amdgcn_cvt_pk_f32_fp8(uu[j], false);
                a0 += f.x;
                a1 += f.y;
            }
        }
        for (; e < end; ++e) {
            unsigned s0 = (unsigned)col[e];
            if (s0 >= (unsigned)n) s0 = 0;
            f32x2 f = __builtin_amdgcn_cvt_pk_f32_fp8((int)hsv[s0 * 64 + lane], false);
            a0 += f.x;
            a1 += f.y;
        }

        float dv = dinv[nd];
        float2 bu = ((const float2*)bias)[lane];
        float r0 = fmaxf(dv * a0 + bu.x, 0.f);
        float r1 = fmaxf(dv * a1 + bu.y, 0.f);
        if (!active) { r0 = 0.f; r1 = 0.f; }
        int row = wave * 4 + i;
        actlds[row * 136 + 2 * lane]     = f2bf(r0);
        actlds[row * 136 + 2 * lane + 1] = f2bf(r1);
    }
    __syncthreads();

    // Phase B: MFMA tile (A from actlds; 16B-aligned: 136*2=272=16*17)
    int quad = lane >> 4;
    int m16 = lane & 15;
    bf16x8 ah[4];
    #pragma unroll
    for (int kt = 0; kt < 4; kt++) {
        const unsigned short* p = &actlds[m16 * 136 + kt * 32 + quad * 8];
        ah[kt] = __builtin_bit_cast(bf16x8, *(const int4*)p);
    }
    float dv4[4];
    #pragma unroll
    for (int reg = 0; reg < 4; reg++) {
        int row = tile0 + quad * 4 + reg;
        if (row > n - 1) row = n - 1;
        dv4[reg] = dinv[row];
    }
    const int4* Wvh = (const int4*)Wth2;
    #pragma unroll
    for (int ntl = 0; ntl < 2; ntl++) {
        int nt = wave * 2 + ntl;
        f32x4 acc = {0.f, 0.f, 0.f, 0.f};
        int brow = (nt * 16 + m16) * 16;
        #pragma unroll
        for (int kt = 0; kt < 4; kt++) {
            bf16x8 bh = __builtin_bit_cast(bf16x8, Wvh[brow + kt * 4 + quad]);
            acc = __builtin_amdgcn_mfma_f32_16x16x32_bf16(ah[kt], bh, acc, 0, 0, 0);
        }
        #pragma unroll
        for (int reg = 0; reg < 4; reg++) {
            float v = acc[reg] * dv4[reg];
            int pk = __builtin_amdgcn_cvt_pk_fp8_f32(v, v, 0, false);
            pack[(quad * 4 + reg) * 128 + nt * 16 + m16] = (unsigned char)(pk & 0xFF);
        }
    }
    __syncthreads();
    const uint32_t* l32 = (const uint32_t*)pack;
    #pragma unroll
    for (int i = 0; i < 2; i++) {
        int idx = i * 256 + threadIdx.x;   // 0..511
        int row = idx >> 5;
        int grow = tile0 + row;
        if (grow < n) hs8out[grow * 32 + (idx & 31)] = l32[idx];
    }
}

// ---- Pull aggregation layer-2 (fp8 hs, pre-scaled) -> pooled partials ---
__launch_bounds__(256)
__global__ void k_agg(const unsigned short* __restrict__ hsv,
                      const int* __restrict__ row_ptr,
                      const int* __restrict__ col, const float* __restrict__ dinv,
                      const float* __restrict__ bias,
                      float* __restrict__ partial, int n, int E) {
    __shared__ float pl[4][128];
    int wave = threadIdx.x >> 6;
    int lane = threadIdx.x & 63;
    int node = blockIdx.x * 4 + wave;
    bool active = (node < n);
    int nd = active ? node : 0;

    f32x2 sf = __builtin_amdgcn_cvt_pk_f32_fp8((int)hsv[nd * 64 + lane], false);
    float a0 = sf.x, a1 = sf.y;

    int e = row_ptr[nd];
    int end = active ? row_ptr[nd + 1] : e;
    if (e < 0) e = 0;
    if (end > E) end = E;

    for (; e + 8 <= end; e += 8) {
        unsigned si[8];
        #pragma unroll
        for (int j = 0; j < 8; j++) {
            unsigned s = (unsigned)col[e + j];
            si[j] = (s < (unsigned)n) ? s : 0u;
        }
        int uu[8];
        #pragma unroll
        for (int j = 0; j < 8; j++) uu[j] = hsv[si[j] * 64 + lane];
        #pragma unroll
        for (int j = 0; j < 8; j++) {
            f32x2 f = __builtin_amdgcn_cvt_pk_f32_fp8(uu[j], false);
            a0 += f.x;
            a1 += f.y;
        }
    }
    for (; e < end; ++e) {
        unsigned s0 = (unsigned)col[e];
        if (s0 >= (unsigned)n) s0 = 0;
        f32x2 f = __builtin_amdgcn_cvt_pk_f32_fp8((int)hsv[s0 * 64 + lane], false);
        a0 += f.x;
        a1 += f.y;
    }

    float dv = dinv[nd];
    float2 bu = ((const float2*)bias)[lane];
    float r0 = fmaxf(dv * a0 + bu.x, 0.f);
    float r1 = fmaxf(dv * a1 + bu.y, 0.f);
    if (!active) { r0 = 0.f; r1 = 0.f; }

    pl[wave][2 * lane]     = r0;
    pl[wave][2 * lane + 1] = r1;
    __syncthreads();
    int t = threadIdx.x;
    if (t < 128) {
        float ps = pl[0][t] + pl[1][t] + pl[2][t] + pl[3][t];
        partial[blockIdx.x * 128 + t] = ps;
    }
}

// ---- fused pooled reduce + FC (last-block pattern) ----------------------
__launch_bounds__(256)
__global__ void k_redfinal(const float* __restrict__ partial, float* __restrict__ pooled,
                           int* __restrict__ done,
                           const float* __restrict__ Wfcf, const float* __restrict__ bfcf,
                           const void* __restrict__ x, void* __restrict__ out,
                           int n, int nbrows, int gblocks) {
    __shared__ float red[8][128];
    int t = threadIdx.x;
    int chunk = (nbrows + gblocks - 1) / gblocks;
    int r0 = blockIdx.x * chunk;
    int r1 = r0 + chunk;
    if (r1 > nbrows) r1 = nbrows;

    float4 acc = {0.f, 0.f, 0.f, 0.f};
    const float4* p4 = (const float4*)partial;
    for (int i = r0 * 32 + t; i < r1 * 32; i += 256) {
        float4 v = p4[i];
        acc.x += v.x; acc.y += v.y; acc.z += v.z; acc.w += v.w;
    }
    int g = t >> 5;
    int fb = (t & 31) * 4;
    red[g][fb]     = acc.x;
    red[g][fb + 1] = acc.y;
    red[g][fb + 2] = acc.z;
    red[g][fb + 3] = acc.w;
    __syncthreads();
    if (t < 128) {
        float s = red[0][t] + red[1][t] + red[2][t] + red[3][t]
                + red[4][t] + red[5][t] + red[6][t] + red[7][t];
        atomicAdd(&pooled[t], s);
    }
    __threadfence();
    __shared__ int lastf;
    if (t == 0) lastf = (atomicAdd(done, 1) == gblocks - 1) ? 1 : 0;
    __syncthreads();
    if (!lastf) return;

    __shared__ int hits;
    __shared__ float pv[128];
    if (t == 0) hits = 0;
    __syncthreads();
    unsigned ew = (((const uint32_t*)x)[t] >> 7) & 0xFFu;
    unsigned long long bl = __ballot(ew >= 0x60u && ew <= 0x90u);
    if ((t & 63) == 0) atomicAdd(&hits, (int)__popcll(bl));
    if (t < 128)
        pv[t] = __hip_atomic_load(&pooled[t], __ATOMIC_RELAXED,
                                  __HIP_MEMORY_SCOPE_AGENT);
    __syncthreads();
    int isbf = (2 * hits > 256);
    if (t < 32) {
        float s = 0.f;
        for (int c = 0; c < 128; ++c) s += pv[c] * Wfcf[c * 32 + t];
        s = s * (1.0f / (float)n) + bfcf[t];
        if (isbf) ((unsigned short*)out)[t] = f2bf(s);
        else      ((float*)out)[t] = s;
    }
}

// ---- Launch -------------------------------------------------------------

extern "C" void kernel_launch(void* const* d_in, const int* in_sizes, int n_in,
                              void* d_out, int out_size, void* d_ws, size_t ws_size,
                              hipStream_t stream) {
    const void* x   = d_in[0];
    const int*  ei  = (const int*)d_in[1];
    const void* W1  = d_in[2];
    const void* b1  = d_in[3];
    const void* W2  = d_in[4];
    const void* b2  = d_in[5];
    const void* Wfc = d_in[6];
    const void* bfc = d_in[7];

    const int n = in_sizes[0] / FEAT;    // 50000
    const int E = in_sizes[1] / 2;       // 800000
    const int nagg = (n + 3) / 4;        // 12500
    const int ntile = (n + 15) / 16;     // 3125
    const int psz  = (n + 7) / 8;        // 6250
    const int nscan = (n + 255) / 256;   // 196
    const int NE   = (E + ECH - 1) / ECH;// 391
    const int gemm_grid = (ntile + 3) / 4; // 782

    char* ws = (char*)d_ws;
    uint32_t*       hs8     = (uint32_t*)(ws);                     // 6.4MB used
    uint32_t*       hs8b    = (uint32_t*)(ws + 12800000);          // 6.4MB (layer-2 hs)
    float*          partial = (float*)(ws + 25600000);             // 6.4MB used
    int*            col     = (int*)(ws + 38400000);               // 3.2MB
    int*            dstb    = (int*)(ws + 41600000);               // 6.4MB (8*CAP)
    int*            srcb    = (int*)(ws + 48000000);               // 6.4MB
    int*            deg     = (int*)(ws + 54400000);               // 200,000
    int*            row_ptr = (int*)(ws + 54600000);               // 200,016
    int*            cursor  = (int*)(ws + 54800016);               // 200,000
    float*          dinv    = (float*)(ws + 55000016);             // 200,000
    unsigned short* Wth1    = (unsigned short*)(ws + 55200016);    // 32,768
    unsigned short* Wth2    = (unsigned short*)(ws + 55232784);    // 32,768
    float*          b1f     = (float*)(ws + 55265552);             // 512
    float*          b2f     = (float*)(ws + 55266064);             // 512
    float*          Wfcf    = (float*)(ws + 55266576);             // 16,384
    float*          bfcf    = (float*)(ws + 55282960);             // 128
    // zero region (one memset): pooled | bcnt | done(+pad) | bsum
    float*          pooled  = (float*)(ws + 55283088);             // 512
    int*            bcnt    = (int*)(ws + 55283600);               // 32
    int*            done    = (int*)(ws + 55283632);               // 4 (+12 pad)
    int*            bsum    = (int*)(ws + 55283648);               // 784

    if (ws_size < 55284448) return;  // diagnostic: zero output => ws too small

    hipMemsetAsync(pooled, 0, 1344, stream);

    // 1) fused prep: edge decode+bucket (+deg zero) | weight/bias prep
    k_prep<<<NE + 82, 256, 0, stream>>>(ei, dstb, srcb, bcnt, deg, E, n, psz, NE,
                                        W1, W2, b1, b2, Wfc, bfc,
                                        Wth1, Wth2, b1f, b2f, Wfcf, bfcf);
    // 2) CSR: degree -> scan (boundaries are the cheap sync -- R11)
    k_degp<<<512, 256, 0, stream>>>(dstb, bcnt, deg);
    k_bsum<<<nscan, 256, 0, stream>>>(deg, bsum, dinv, n);
    k_bapply2<<<nscan, 256, 0, stream>>>(deg, bsum, row_ptr, cursor, n, nscan);
    // 3) fused: scatter || GEMM layer-1 (both dep only on bapply)
    k_sg<<<SCB + gemm_grid, 256, 0, stream>>>(dstb, srcb, bcnt, cursor, col, E,
                                              x, Wth1, dinv, hs8, n);
    // 4) fused agg-1 + GEMM-2 (act never hits global; one fp8 round-trip less)
    k_agg1gemm2<<<ntile, 256, 0, stream>>>((const unsigned short*)hs8, row_ptr,
                                           col, dinv, b1f, Wth2, hs8b, n, E);
    // 5) agg-2 -> pooled partials
    k_agg<<<nagg, 256, 0, stream>>>((const unsigned short*)hs8b, row_ptr, col,
                                    dinv, b2f, partial, n, E);
    // 6) fused pooled-reduce + FC
    k_redfinal<<<100, 256, 0, stream>>>(partial, pooled, done, Wfcf, bfcf,
                                        x, d_out, n, nagg, 100);
}